// Round 11
// baseline (60.744 us; speedup 1.0000x reference)
//
#include <hip/hip_runtime.h>
#include <stdint.h>

#define D 128
#define NTHR 512
#define RPB 32  // rows per block: 8 waves x 4 rows(16 lanes each)

typedef float f2 __attribute__((ext_vector_type(2)));
typedef float f4 __attribute__((ext_vector_type(4)));
typedef __fp16 h2 __attribute__((ext_vector_type(2)));

// ws layout (uint16 elements): wmu[D*D] | wls[D*D] | w1t[D*D]
#define WS_NEED (size_t)(D * D * 6)

__device__ __forceinline__ h2 bch2(uint32_t u) { return __builtin_bit_cast(h2, u); }
__device__ __forceinline__ float fdot2f(h2 a, h2 b, float c) {
  return __builtin_amdgcn_fdot2(a, b, c, false);
}
template <int CTRL>
__device__ __forceinline__ float dppmov(float v) {
  return __int_as_float(
      __builtin_amdgcn_update_dpp(0, __float_as_int(v), CTRL, 0xf, 0xf, true));
}
#define DPP_ADD(v, ctrl) (v) += dppmov<(ctrl)>((v))

// ================= prep: mask + transpose + f16-pack into ws =================
__global__ __launch_bounds__(256)
void iaf_prep(const float* __restrict__ W1, const float* __restrict__ Wmu,
              const float* __restrict__ Wls, uint16_t* __restrict__ ws) {
  const int idx = blockIdx.x * 256 + threadIdx.x;
  if (idx >= D * D) return;
  const int i = idx >> 7, j = idx & (D - 1);
  const __fp16 mu = (__fp16)((j < i) ? Wmu[idx] : 0.f);
  const __fp16 ls = (__fp16)((j < i) ? Wls[idx] : 0.f);
  const __fp16 w1 = (__fp16)((j > i) ? W1[j * D + i] : 0.f);  // column i of W1
  ws[idx] = __builtin_bit_cast(uint16_t, mu);
  ws[D * D + idx] = __builtin_bit_cast(uint16_t, ls);
  ws[2 * D * D + idx] = __builtin_bit_cast(uint16_t, w1);
}

// ===== main: 16 lanes/row, LDS f16 weights, all-DPP reduce, reg double-buffer,
// ===== ZERO branches in the loop (masked weights are exact zeros -> math identical)
#define LOAD4(P, IT)                                                  \
  {                                                                   \
    const int ii_ = (IT) * 4;                                         \
    P##wm0 = *(const uint4*)(wmu_s + (ii_ + 0) * D + m8);             \
    P##wm1 = *(const uint4*)(wmu_s + (ii_ + 1) * D + m8);             \
    P##wm2 = *(const uint4*)(wmu_s + (ii_ + 2) * D + m8);             \
    P##wm3 = *(const uint4*)(wmu_s + (ii_ + 3) * D + m8);             \
    P##wl0 = *(const uint4*)(wls_s + (ii_ + 0) * D + m8);             \
    P##wl1 = *(const uint4*)(wls_s + (ii_ + 1) * D + m8);             \
    P##wl2 = *(const uint4*)(wls_s + (ii_ + 2) * D + m8);             \
    P##wl3 = *(const uint4*)(wls_s + (ii_ + 3) * D + m8);             \
    P##w10 = *(const uint4*)(w1t_s + (ii_ + 0) * D + m8);             \
    P##w11 = *(const uint4*)(w1t_s + (ii_ + 1) * D + m8);             \
    P##w12 = *(const uint4*)(w1t_s + (ii_ + 2) * D + m8);             \
    P##w13 = *(const uint4*)(w1t_s + (ii_ + 3) * D + m8);             \
    P##x = *(const f4*)(xs_row + ii_);                                \
    P##b01 = *(const f4*)(bias2 + 2 * ii_);                           \
    P##b23 = *(const f4*)(bias2 + 2 * ii_ + 4);                       \
  }

#define STEPX(I, WM, WL, WV, XE, BMU, BLS, ZRI)                         \
  {                                                                     \
    const h2 h01_ = __builtin_elementwise_max(a01, hz);                 \
    const h2 h23_ = __builtin_elementwise_max(a23, hz);                 \
    const h2 h45_ = __builtin_elementwise_max(a45, hz);                 \
    const h2 h67_ = __builtin_elementwise_max(a67, hz);                 \
    float mu_p = fdot2f(h01_, bch2(WM.x), 0.f);                         \
    mu_p = fdot2f(h23_, bch2(WM.y), mu_p);                              \
    mu_p = fdot2f(h45_, bch2(WM.z), mu_p);                              \
    mu_p = fdot2f(h67_, bch2(WM.w), mu_p);                              \
    float ls_p = fdot2f(h01_, bch2(WL.x), 0.f);                         \
    ls_p = fdot2f(h23_, bch2(WL.y), ls_p);                              \
    ls_p = fdot2f(h45_, bch2(WL.z), ls_p);                              \
    ls_p = fdot2f(h67_, bch2(WL.w), ls_p);                              \
    /* folded 16-lane reduce: lanes 0-7 carry mu, 8-15 carry ls */      \
    float fold = hi ? ls_p : mu_p;                                      \
    fold += dppmov<0x128>(hi ? mu_p : ls_p); /* row_ror:8 == xor8 */    \
    DPP_ADD(fold, 0xB1);  /* quad_perm xor1 */                          \
    DPP_ADD(fold, 0x4E);  /* quad_perm xor2 */                          \
    DPP_ADD(fold, 0x141); /* row_half_mirror */                         \
    const float other = dppmov<0x128>(fold);                            \
    const float mu_t = (hi ? other : fold) + (BMU);                     \
    const float ls_t = (hi ? fold : other) + (BLS);                     \
    const float zi = fmaf((XE), __expf(ls_t), mu_t); /* replicated */   \
    ldj += ls_t;                                                        \
    if (m == ((I) >> 3)) ZRI = zi;                                      \
    const h2 z2_ = __builtin_amdgcn_cvt_pkrtz(zi, zi);                  \
    a01 = __builtin_elementwise_fma(z2_, bch2(WV.x), a01);              \
    a23 = __builtin_elementwise_fma(z2_, bch2(WV.y), a23);              \
    a45 = __builtin_elementwise_fma(z2_, bch2(WV.z), a45);              \
    a67 = __builtin_elementwise_fma(z2_, bch2(WV.w), a67);              \
  }

__global__ __launch_bounds__(NTHR, 2)
void iaf_main(const float* __restrict__ x, const float* __restrict__ b1,
              const float* __restrict__ bmu, const float* __restrict__ bls,
              const uint16_t* __restrict__ ws, float* __restrict__ out, int B) {
  __shared__ uint16_t wmu_s[D * D];  // 32KB each
  __shared__ uint16_t wls_s[D * D];
  __shared__ uint16_t w1t_s[D * D];
  __shared__ float xs[RPB][D + 4];   // padded rows
  __shared__ float bias2[2 * D];     // {bmu[i], bls[i]} interleaved

  const int tid = threadIdx.x;
  const int r0 = blockIdx.x * RPB;
  // ---- stage weights ws -> LDS (b128 copies; fully initializes all LDS) ----
  {
    const uint4* s0 = (const uint4*)(ws);
    const uint4* s1 = (const uint4*)(ws + D * D);
    const uint4* s2 = (const uint4*)(ws + 2 * D * D);
    uint4* d0 = (uint4*)wmu_s;
    uint4* d1 = (uint4*)wls_s;
    uint4* d2 = (uint4*)w1t_s;
#pragma unroll
    for (int k = 0; k < 4; ++k) {
      d0[tid + k * NTHR] = s0[tid + k * NTHR];
      d1[tid + k * NTHR] = s1[tid + k * NTHR];
      d2[tid + k * NTHR] = s2[tid + k * NTHR];
    }
  }
  // ---- stage x rows + biases ----
  {
    const int r = tid >> 4;
    const int c = (tid & 15) * 8;
    const f4 t0 = *(const f4*)(x + (size_t)(r0 + r) * D + c);
    const f4 t1 = *(const f4*)(x + (size_t)(r0 + r) * D + c + 4);
    *(f4*)(&xs[r][c]) = t0;
    *(f4*)(&xs[r][c + 4]) = t1;
    if (tid < D) {
      bias2[2 * tid] = bmu[tid];
      bias2[2 * tid + 1] = bls[tid];
    }
  }

  const int m = tid & 15;
  const int m8 = m << 3;
  const bool hi = (m & 8) != 0;
  const int row = r0 + (tid >> 4);
  const float* __restrict__ xs_row = xs[tid >> 4];

  // a = b1 chunk, in f16 pairs
  h2 a01, a23, a45, a67;
  {
    const f4 t0 = *(const f4*)(b1 + m8);
    const f4 t1 = *(const f4*)(b1 + m8 + 4);
    a01 = __builtin_amdgcn_cvt_pkrtz(t0.x, t0.y);
    a23 = __builtin_amdgcn_cvt_pkrtz(t0.z, t0.w);
    a45 = __builtin_amdgcn_cvt_pkrtz(t1.x, t1.y);
    a67 = __builtin_amdgcn_cvt_pkrtz(t1.z, t1.w);
  }
  const h2 hz = bch2(0u);
  float zr[8];
  float ldj = 0.f;

  uint4 Awm0, Awm1, Awm2, Awm3, Awl0, Awl1, Awl2, Awl3, Aw10, Aw11, Aw12, Aw13;
  uint4 Bwm0, Bwm1, Bwm2, Bwm3, Bwl0, Bwl1, Bwl2, Bwl3, Bw10, Bw11, Bw12, Bw13;
  f4 Ax, Bx, Ab01, Ab23, Bb01, Bb23;

  __syncthreads();

  LOAD4(A, 0)

#pragma unroll 1
  for (int it = 0; it < 32; it += 2) {
    const int i0 = it * 4;
    LOAD4(B, it + 1)  // in flight while computing A
    STEPX(i0 + 0, Awm0, Awl0, Aw10, Ax.x, Ab01.x, Ab01.y, zr[0])
    STEPX(i0 + 1, Awm1, Awl1, Aw11, Ax.y, Ab01.z, Ab01.w, zr[1])
    STEPX(i0 + 2, Awm2, Awl2, Aw12, Ax.z, Ab23.x, Ab23.y, zr[2])
    STEPX(i0 + 3, Awm3, Awl3, Aw13, Ax.w, Ab23.z, Ab23.w, zr[3])
    const int nit = (it + 2 < 32) ? it + 2 : 31;
    LOAD4(A, nit)     // in flight while computing B
    STEPX(i0 + 4, Bwm0, Bwl0, Bw10, Bx.x, Bb01.x, Bb01.y, zr[4])
    STEPX(i0 + 5, Bwm1, Bwl1, Bw11, Bx.y, Bb01.z, Bb01.w, zr[5])
    STEPX(i0 + 6, Bwm2, Bwl2, Bw12, Bx.z, Bb23.x, Bb23.y, zr[6])
    STEPX(i0 + 7, Bwm3, Bwl3, Bw13, Bx.w, Bb23.z, Bb23.w, zr[7])
  }

  // ---- stores: lane m owns columns 8m..8m+7 of its row ----
  f4 o0, o1;
  o0.x = zr[0]; o0.y = zr[1]; o0.z = zr[2]; o0.w = zr[3];
  o1.x = zr[4]; o1.y = zr[5]; o1.z = zr[6]; o1.w = zr[7];
  float* zo = out + (size_t)row * D + m8;
  *(f4*)(zo) = o0;
  *(f4*)(zo + 4) = o1;
  if (m == 0) out[(size_t)B * D + row] = ldj;
}

// ================= fallback (proven R3 kernel, if ws too small) =================
#define FNTHR 256
#define FRPB 16
#define W1S 136
__device__ __forceinline__ uint16_t f2bf(float f) {
  uint32_t u = __float_as_uint(f);
  u += 0x7fffu + ((u >> 16) & 1u);
  return (uint16_t)(u >> 16);
}
__device__ __forceinline__ f2 unpk(uint32_t u) {
  f2 r;
  r.x = __uint_as_float(u << 16);
  r.y = __uint_as_float(u & 0xffff0000u);
  return r;
}
#define RED16F(v)      \
  do {                 \
    DPP_ADD(v, 0xB1);  \
    DPP_ADD(v, 0x4E);  \
    DPP_ADD(v, 0x124); \
    DPP_ADD(v, 0x128); \
  } while (0)
#define FSTEP(I, XE, ZRE, MKE, WM0, WM1, WL0, WL1)                  \
  {                                                                 \
    const float bmu_i = bmu[(I)];                                   \
    const float bls_i = bls[(I)];                                   \
    const f2 h0 = __builtin_elementwise_max(A0, (f2)0.f);           \
    const f2 h1 = __builtin_elementwise_max(A1, (f2)0.f);           \
    const f2 h2_ = __builtin_elementwise_max(A2, (f2)0.f);          \
    const f2 h3 = __builtin_elementwise_max(A3, (f2)0.f);           \
    const f2 q0 = h0 * mk0, q1 = h1 * mk1;                          \
    const f2 q2 = h2_ * mk2, q3 = h3 * mk3;                         \
    f2 am = q0 * WM0.xy;                                            \
    f2 al = q0 * WL0.xy;                                            \
    am = __builtin_elementwise_fma(q1, WM0.zw, am);                 \
    al = __builtin_elementwise_fma(q1, WL0.zw, al);                 \
    am = __builtin_elementwise_fma(q2, WM1.xy, am);                 \
    al = __builtin_elementwise_fma(q2, WL1.xy, al);                 \
    am = __builtin_elementwise_fma(q3, WM1.zw, am);                 \
    al = __builtin_elementwise_fma(q3, WL1.zw, al);                 \
    float mu_p = am.x + am.y;                                       \
    float ls_p = al.x + al.y;                                       \
    {                                                               \
      const int pfr = ((I) + 2 < D) ? (I) + 2 : D - 1;              \
      WM0 = *(const f4*)(wmup + pfr * D);                           \
      WM1 = *(const f4*)(wmup + pfr * D + 4);                       \
      WL0 = *(const f4*)(wlsp + pfr * D);                           \
      WL1 = *(const f4*)(wlsp + pfr * D + 4);                       \
    }                                                               \
    RED16F(mu_p);                                                   \
    RED16F(ls_p);                                                   \
    const float mu_t = mu_p + bmu_i;                                \
    const float ls_t = ls_p + bls_i;                                \
    const float zi = fmaf((XE), __expf(ls_t), mu_t);                \
    ldj += ls_t;                                                    \
    const uint4 wv = *(const uint4*)(w1p + (I)*W1S);                \
    if (own) {                                                      \
      ZRE = zi;                                                     \
      MKE = 1.f;                                                    \
    }                                                               \
    f2 zz;                                                          \
    zz.x = zi;                                                      \
    zz.y = zi;                                                      \
    A0 = __builtin_elementwise_fma(zz, unpk(wv.x), A0);             \
    A1 = __builtin_elementwise_fma(zz, unpk(wv.y), A1);             \
    A2 = __builtin_elementwise_fma(zz, unpk(wv.z), A2);             \
    A3 = __builtin_elementwise_fma(zz, unpk(wv.w), A3);             \
  }

__global__ __launch_bounds__(FNTHR, 2)
void iaf_fb(const float* __restrict__ x, const float* __restrict__ W1,
            const float* __restrict__ b1, const float* __restrict__ Wmu,
            const float* __restrict__ bmu, const float* __restrict__ Wls,
            const float* __restrict__ bls, float* __restrict__ out, int B) {
  __shared__ uint16_t w1c[D * W1S];
  const int tid = threadIdx.x;
  for (int idx = tid; idx < D * D; idx += FNTHR) {
    const int p = idx >> 7, q = idx & (D - 1);
    w1c[q * W1S + p] = f2bf((p > q) ? W1[idx] : 0.f);
  }
  __syncthreads();
  const int lane = tid & 63;
  const int m = lane & 15;
  const int row = blockIdx.x * FRPB + (tid >> 4);
  const float* __restrict__ xp = x + (size_t)row * D;
  const float* __restrict__ wmup = Wmu + m * 8;
  const float* __restrict__ wlsp = Wls + m * 8;
  const uint16_t* __restrict__ w1p = w1c + m * 8;
  f2 A0, A1, A2, A3;
  {
    const f4 t0 = *(const f4*)(b1 + m * 8);
    const f4 t1 = *(const f4*)(b1 + m * 8 + 4);
    A0 = t0.xy; A1 = t0.zw; A2 = t1.xy; A3 = t1.zw;
  }
  f2 mk0 = (f2)0.f, mk1 = (f2)0.f, mk2 = (f2)0.f, mk3 = (f2)0.f;
  float zr0 = 0, zr1 = 0, zr2 = 0, zr3 = 0, zr4 = 0, zr5 = 0, zr6 = 0, zr7 = 0;
  float ldj = 0.f;
  f4 wmA0 = *(const f4*)(wmup);
  f4 wmA1 = *(const f4*)(wmup + 4);
  f4 wlA0 = *(const f4*)(wlsp);
  f4 wlA1 = *(const f4*)(wlsp + 4);
  f4 wmB0 = *(const f4*)(wmup + D);
  f4 wmB1 = *(const f4*)(wmup + D + 4);
  f4 wlB0 = *(const f4*)(wlsp + D);
  f4 wlB1 = *(const f4*)(wlsp + D + 4);
  f4 x4a = *(const f4*)(xp);
  f4 x4b;
  for (int ib = 0; ib < 16; ++ib) {
    const int i0 = ib * 8;
    const bool own = (m == ib);
    x4b = *(const f4*)(xp + i0 + 4);
    FSTEP(i0 + 0, x4a.x, zr0, mk0.x, wmA0, wmA1, wlA0, wlA1);
    FSTEP(i0 + 1, x4a.y, zr1, mk0.y, wmB0, wmB1, wlB0, wlB1);
    FSTEP(i0 + 2, x4a.z, zr2, mk1.x, wmA0, wmA1, wlA0, wlA1);
    FSTEP(i0 + 3, x4a.w, zr3, mk1.y, wmB0, wmB1, wlB0, wlB1);
    {
      const int nx = (i0 + 8 < D) ? i0 + 8 : D - 4;
      x4a = *(const f4*)(xp + nx);
    }
    FSTEP(i0 + 4, x4b.x, zr4, mk2.x, wmA0, wmA1, wlA0, wlA1);
    FSTEP(i0 + 5, x4b.y, zr5, mk2.y, wmB0, wmB1, wlB0, wlB1);
    FSTEP(i0 + 6, x4b.z, zr6, mk3.x, wmA0, wmA1, wlA0, wlA1);
    FSTEP(i0 + 7, x4b.w, zr7, mk3.y, wmB0, wmB1, wlB0, wlB1);
  }
  f4 o0, o1;
  o0.x = zr0; o0.y = zr1; o0.z = zr2; o0.w = zr3;
  o1.x = zr4; o1.y = zr5; o1.z = zr6; o1.w = zr7;
  float* zo = out + (size_t)row * D + m * 8;
  *(f4*)(zo) = o0;
  *(f4*)(zo + 4) = o1;
  if (m == 0) out[(size_t)B * D + row] = ldj;
}

extern "C" void kernel_launch(void* const* d_in, const int* in_sizes, int n_in,
                              void* d_out, int out_size, void* d_ws, size_t ws_size,
                              hipStream_t stream) {
  const float* x   = (const float*)d_in[0];
  const float* W1  = (const float*)d_in[1];
  const float* b1  = (const float*)d_in[2];
  const float* Wmu = (const float*)d_in[3];
  const float* bmu = (const float*)d_in[4];
  const float* Wls = (const float*)d_in[5];
  const float* bls = (const float*)d_in[6];
  float* out = (float*)d_out;

  const int B = in_sizes[0] / D;  // 8192

  if (ws_size >= WS_NEED) {
    iaf_prep<<<(D * D + 255) / 256, 256, 0, stream>>>(W1, Wmu, Wls, (uint16_t*)d_ws);
    const int grid = (B + RPB - 1) / RPB;  // 256
    iaf_main<<<grid, NTHR, 0, stream>>>(x, b1, bmu, bls, (const uint16_t*)d_ws, out, B);
  } else {
    const int grid = (B + FRPB - 1) / FRPB;  // 512
    iaf_fb<<<grid, FNTHR, 0, stream>>>(x, W1, b1, Wmu, bmu, Wls, bls, out, B);
  }
}

// Round 12
// 44.542 us; speedup vs baseline: 1.3637x; 1.3637x over previous
//
#include <hip/hip_runtime.h>
#include <stdint.h>

#define D 128

typedef float f2 __attribute__((ext_vector_type(2)));
typedef float f4 __attribute__((ext_vector_type(4)));

__device__ __forceinline__ uint16_t f2bf(float f) {
  uint32_t u = __float_as_uint(f);
  u += 0x7fffu + ((u >> 16) & 1u);  // RNE
  return (uint16_t)(u >> 16);
}
__device__ __forceinline__ uint32_t pkbf(float a, float b) {
  return (uint32_t)f2bf(a) | ((uint32_t)f2bf(b) << 16);
}
__device__ __forceinline__ f2 unpkbf(uint32_t u) {
  f2 r;
  r.x = __uint_as_float(u << 16);
  r.y = __uint_as_float(u & 0xffff0000u);
  return r;
}
__device__ __forceinline__ float rdlane(float v, int l) {
  return __int_as_float(__builtin_amdgcn_readlane(__float_as_int(v), l));
}

// ws layout: 3 tables of uint4[32*64] (32KB each): WMU4 | WLS4 | W14.
// entry[jb*64+l].c = pack(bf16 M[2l][4jb+c], bf16 M[2l+1][4jb+c]), masked j<row.
#define WS_NEED (size_t)(3 * 32 * 64 * 16)  // 98304

// ================= prep: mask + column-pack into ws =================
__global__ __launch_bounds__(256)
void iaf_prep(const float* __restrict__ W1, const float* __restrict__ Wmu,
              const float* __restrict__ Wls, uint4* __restrict__ ws) {
  const int t = blockIdx.x * 256 + threadIdx.x;
  if (t >= 32 * 64) return;
  const int jb = t >> 6, l = t & 63;
  const int k0 = 2 * l, k1 = 2 * l + 1;
  uint32_t mm[4], ll[4], ww[4];
#pragma unroll
  for (int c = 0; c < 4; ++c) {
    const int j = jb * 4 + c;
    const float m0 = (j < k0) ? Wmu[k0 * D + j] : 0.f;
    const float m1 = (j < k1) ? Wmu[k1 * D + j] : 0.f;
    const float s0 = (j < k0) ? Wls[k0 * D + j] : 0.f;
    const float s1 = (j < k1) ? Wls[k1 * D + j] : 0.f;
    const float w0 = (j < k0) ? W1[k0 * D + j] : 0.f;
    const float w1_ = (j < k1) ? W1[k1 * D + j] : 0.f;
    mm[c] = pkbf(m0, m1);
    ll[c] = pkbf(s0, s1);
    ww[c] = pkbf(w0, w1_);
  }
  uint4 m4, l4, w4;
  m4.x = mm[0]; m4.y = mm[1]; m4.z = mm[2]; m4.w = mm[3];
  l4.x = ll[0]; l4.y = ll[1]; l4.z = ll[2]; l4.w = ll[3];
  w4.x = ww[0]; w4.y = ww[1]; w4.z = ww[2]; w4.w = ww[3];
  ws[t] = m4;
  ws[2048 + t] = l4;
  ws[4096 + t] = w4;
}

// ========== main: column sweep, 64 lanes/row, 2 rows/wave, no reductions ==========
#define SEL(U, c) ((c) == 0 ? (U).x : (c) == 1 ? (U).y : (c) == 2 ? (U).z : (U).w)
#define E(V, c) (((c) & 1) ? (V).y : (V).x)

#define STEP(c, M4, L4, W4, JB)                                           \
  {                                                                       \
    const int Ln = (JB) * 2 + ((c) >> 1);                                 \
    const f2 wm = unpkbf(SEL(M4, c));                                     \
    const f2 wl = unpkbf(SEL(L4, c));                                     \
    const f2 wv = unpkbf(SEL(W4, c));                                     \
    const float hA = fmaxf(E(paA, c), 0.f);                               \
    const float hB = fmaxf(E(paB, c), 0.f);                               \
    const float zA =                                                      \
        fmaf(E(xA, c), __expf(E(plsA, c) + E(blsR, c)), E(pmuA, c) + E(bmuR, c)); \
    const float zB =                                                      \
        fmaf(E(xB, c), __expf(E(plsB, c) + E(blsR, c)), E(pmuB, c) + E(bmuR, c)); \
    const float szA = rdlane(zA, Ln);                                     \
    const float shA = rdlane(hA, Ln);                                     \
    const float szB = rdlane(zB, Ln);                                     \
    const float shB = rdlane(hB, Ln);                                     \
    f2 t;                                                                 \
    t.x = szA; t.y = szA;                                                 \
    paA = __builtin_elementwise_fma(t, wv, paA);                          \
    t.x = shA; t.y = shA;                                                 \
    pmuA = __builtin_elementwise_fma(t, wm, pmuA);                        \
    plsA = __builtin_elementwise_fma(t, wl, plsA);                        \
    t.x = szB; t.y = szB;                                                 \
    paB = __builtin_elementwise_fma(t, wv, paB);                          \
    t.x = shB; t.y = shB;                                                 \
    pmuB = __builtin_elementwise_fma(t, wm, pmuB);                        \
    plsB = __builtin_elementwise_fma(t, wl, plsB);                        \
  }

__global__ __launch_bounds__(1024, 1)
void iaf_main(const float* __restrict__ x, const float* __restrict__ b1,
              const float* __restrict__ bmu, const float* __restrict__ bls,
              const uint4* __restrict__ ws, float* __restrict__ out, int B) {
  __shared__ uint4 wsh[3 * 2048];  // 96KB: wmu4 | wls4 | w14

  const int tid = threadIdx.x;
  // ---- stage all three tables (straight uint4 copy) ----
#pragma unroll
  for (int k = 0; k < 6; ++k) wsh[tid + k * 1024] = ws[tid + k * 1024];

  const int lane = tid & 63;
  const int wave = tid >> 6;
  const int rA = blockIdx.x * 32 + wave * 2;
  const int rB = rA + 1;
  const int l2 = lane * 2;

  const f2 xA = *(const f2*)(x + (size_t)rA * D + l2);
  const f2 xB = *(const f2*)(x + (size_t)rB * D + l2);
  const f2 b1R = *(const f2*)(b1 + l2);
  const f2 bmuR = *(const f2*)(bmu + l2);
  const f2 blsR = *(const f2*)(bls + l2);

  f2 paA = b1R, paB = b1R;          // running a (frozen at own index)
  f2 pmuA = (f2)0.f, pmuB = (f2)0.f;
  f2 plsA = (f2)0.f, plsB = (f2)0.f;

  const uint4* wmu4s = wsh;
  const uint4* wls4s = wsh + 2048;
  const uint4* w14s = wsh + 4096;

  __syncthreads();

  uint4 mC = wmu4s[lane], lC = wls4s[lane], wC = w14s[lane];

#pragma unroll 1
  for (int jb = 0; jb < 32; ++jb) {
    const int nb = (jb + 1 < 32) ? jb + 1 : 31;
    const uint4 mN = wmu4s[nb * 64 + lane];
    const uint4 lN = wls4s[nb * 64 + lane];
    const uint4 wN = w14s[nb * 64 + lane];
    STEP(0, mC, lC, wC, jb)
    STEP(1, mC, lC, wC, jb)
    STEP(2, mC, lC, wC, jb)
    STEP(3, mC, lC, wC, jb)
    mC = mN; lC = lN; wC = wN;
  }

  // ---- outputs from frozen accumulators ----
  f2 zfA, zfB;
  zfA.x = fmaf(xA.x, __expf(plsA.x + blsR.x), pmuA.x + bmuR.x);
  zfA.y = fmaf(xA.y, __expf(plsA.y + blsR.y), pmuA.y + bmuR.y);
  zfB.x = fmaf(xB.x, __expf(plsB.x + blsR.x), pmuB.x + bmuR.x);
  zfB.y = fmaf(xB.y, __expf(plsB.y + blsR.y), pmuB.y + bmuR.y);
  *(f2*)(out + (size_t)rA * D + l2) = zfA;
  *(f2*)(out + (size_t)rB * D + l2) = zfB;

  float ldjA = (plsA.x + blsR.x) + (plsA.y + blsR.y);
  float ldjB = (plsB.x + blsR.x) + (plsB.y + blsR.y);
#pragma unroll
  for (int m = 1; m < 64; m <<= 1) {
    ldjA += __shfl_xor(ldjA, m);
    ldjB += __shfl_xor(ldjB, m);
  }
  if (lane == 0) {
    out[(size_t)B * D + rA] = ldjA;
    out[(size_t)B * D + rB] = ldjB;
  }
}

// ================= fallback (proven R3 kernel, if ws too small) =================
#define FNTHR 256
#define FRPB 16
#define W1S 136
template <int CTRL>
__device__ __forceinline__ float dppmov(float v) {
  return __int_as_float(
      __builtin_amdgcn_update_dpp(0, __float_as_int(v), CTRL, 0xf, 0xf, true));
}
#define DPP_ADD(v, ctrl) (v) += dppmov<(ctrl)>((v))
__device__ __forceinline__ f2 unpk(uint32_t u) {
  f2 r;
  r.x = __uint_as_float(u << 16);
  r.y = __uint_as_float(u & 0xffff0000u);
  return r;
}
#define RED16F(v)      \
  do {                 \
    DPP_ADD(v, 0xB1);  \
    DPP_ADD(v, 0x4E);  \
    DPP_ADD(v, 0x124); \
    DPP_ADD(v, 0x128); \
  } while (0)
#define FSTEP(I, XE, ZRE, MKE, WM0, WM1, WL0, WL1)                  \
  {                                                                 \
    const float bmu_i = bmu[(I)];                                   \
    const float bls_i = bls[(I)];                                   \
    const f2 h0 = __builtin_elementwise_max(A0, (f2)0.f);           \
    const f2 h1 = __builtin_elementwise_max(A1, (f2)0.f);           \
    const f2 h2_ = __builtin_elementwise_max(A2, (f2)0.f);          \
    const f2 h3 = __builtin_elementwise_max(A3, (f2)0.f);           \
    const f2 q0 = h0 * mk0, q1 = h1 * mk1;                          \
    const f2 q2 = h2_ * mk2, q3 = h3 * mk3;                         \
    f2 am = q0 * WM0.xy;                                            \
    f2 al = q0 * WL0.xy;                                            \
    am = __builtin_elementwise_fma(q1, WM0.zw, am);                 \
    al = __builtin_elementwise_fma(q1, WL0.zw, al);                 \
    am = __builtin_elementwise_fma(q2, WM1.xy, am);                 \
    al = __builtin_elementwise_fma(q2, WL1.xy, al);                 \
    am = __builtin_elementwise_fma(q3, WM1.zw, am);                 \
    al = __builtin_elementwise_fma(q3, WL1.zw, al);                 \
    float mu_p = am.x + am.y;                                       \
    float ls_p = al.x + al.y;                                       \
    {                                                               \
      const int pfr = ((I) + 2 < D) ? (I) + 2 : D - 1;              \
      WM0 = *(const f4*)(wmup + pfr * D);                           \
      WM1 = *(const f4*)(wmup + pfr * D + 4);                       \
      WL0 = *(const f4*)(wlsp + pfr * D);                           \
      WL1 = *(const f4*)(wlsp + pfr * D + 4);                       \
    }                                                               \
    RED16F(mu_p);                                                   \
    RED16F(ls_p);                                                   \
    const float mu_t = mu_p + bmu_i;                                \
    const float ls_t = ls_p + bls_i;                                \
    const float zi = fmaf((XE), __expf(ls_t), mu_t);                \
    ldj += ls_t;                                                    \
    const uint4 wv = *(const uint4*)(w1p + (I)*W1S);                \
    if (own) {                                                      \
      ZRE = zi;                                                     \
      MKE = 1.f;                                                    \
    }                                                               \
    f2 zz;                                                          \
    zz.x = zi;                                                      \
    zz.y = zi;                                                      \
    A0 = __builtin_elementwise_fma(zz, unpk(wv.x), A0);             \
    A1 = __builtin_elementwise_fma(zz, unpk(wv.y), A1);             \
    A2 = __builtin_elementwise_fma(zz, unpk(wv.z), A2);             \
    A3 = __builtin_elementwise_fma(zz, unpk(wv.w), A3);             \
  }

__global__ __launch_bounds__(FNTHR, 2)
void iaf_fb(const float* __restrict__ x, const float* __restrict__ W1,
            const float* __restrict__ b1, const float* __restrict__ Wmu,
            const float* __restrict__ bmu, const float* __restrict__ Wls,
            const float* __restrict__ bls, float* __restrict__ out, int B) {
  __shared__ uint16_t w1c[D * W1S];
  const int tid = threadIdx.x;
  for (int idx = tid; idx < D * D; idx += FNTHR) {
    const int p = idx >> 7, q = idx & (D - 1);
    w1c[q * W1S + p] = f2bf((p > q) ? W1[idx] : 0.f);
  }
  __syncthreads();
  const int lane = tid & 63;
  const int m = lane & 15;
  const int row = blockIdx.x * FRPB + (tid >> 4);
  const float* __restrict__ xp = x + (size_t)row * D;
  const float* __restrict__ wmup = Wmu + m * 8;
  const float* __restrict__ wlsp = Wls + m * 8;
  const uint16_t* __restrict__ w1p = w1c + m * 8;
  f2 A0, A1, A2, A3;
  {
    const f4 t0 = *(const f4*)(b1 + m * 8);
    const f4 t1 = *(const f4*)(b1 + m * 8 + 4);
    A0 = t0.xy; A1 = t0.zw; A2 = t1.xy; A3 = t1.zw;
  }
  f2 mk0 = (f2)0.f, mk1 = (f2)0.f, mk2 = (f2)0.f, mk3 = (f2)0.f;
  float zr0 = 0, zr1 = 0, zr2 = 0, zr3 = 0, zr4 = 0, zr5 = 0, zr6 = 0, zr7 = 0;
  float ldj = 0.f;
  f4 wmA0 = *(const f4*)(wmup);
  f4 wmA1 = *(const f4*)(wmup + 4);
  f4 wlA0 = *(const f4*)(wlsp);
  f4 wlA1 = *(const f4*)(wlsp + 4);
  f4 wmB0 = *(const f4*)(wmup + D);
  f4 wmB1 = *(const f4*)(wmup + D + 4);
  f4 wlB0 = *(const f4*)(wlsp + D);
  f4 wlB1 = *(const f4*)(wlsp + D + 4);
  f4 x4a = *(const f4*)(xp);
  f4 x4b;
  for (int ib = 0; ib < 16; ++ib) {
    const int i0 = ib * 8;
    const bool own = (m == ib);
    x4b = *(const f4*)(xp + i0 + 4);
    FSTEP(i0 + 0, x4a.x, zr0, mk0.x, wmA0, wmA1, wlA0, wlA1);
    FSTEP(i0 + 1, x4a.y, zr1, mk0.y, wmB0, wmB1, wlB0, wlB1);
    FSTEP(i0 + 2, x4a.z, zr2, mk1.x, wmA0, wmA1, wlA0, wlA1);
    FSTEP(i0 + 3, x4a.w, zr3, mk1.y, wmB0, wmB1, wlB0, wlB1);
    {
      const int nx = (i0 + 8 < D) ? i0 + 8 : D - 4;
      x4a = *(const f4*)(xp + nx);
    }
    FSTEP(i0 + 4, x4b.x, zr4, mk2.x, wmA0, wmA1, wlA0, wlA1);
    FSTEP(i0 + 5, x4b.y, zr5, mk2.y, wmB0, wmB1, wlB0, wlB1);
    FSTEP(i0 + 6, x4b.z, zr6, mk3.x, wmA0, wmA1, wlA0, wlA1);
    FSTEP(i0 + 7, x4b.w, zr7, mk3.y, wmB0, wmB1, wlB0, wlB1);
  }
  f4 o0, o1;
  o0.x = zr0; o0.y = zr1; o0.z = zr2; o0.w = zr3;
  o1.x = zr4; o1.y = zr5; o1.z = zr6; o1.w = zr7;
  float* zo = out + (size_t)row * D + m * 8;
  *(f4*)(zo) = o0;
  *(f4*)(zo + 4) = o1;
  if (m == 0) out[(size_t)B * D + row] = ldj;
}

extern "C" void kernel_launch(void* const* d_in, const int* in_sizes, int n_in,
                              void* d_out, int out_size, void* d_ws, size_t ws_size,
                              hipStream_t stream) {
  const float* x   = (const float*)d_in[0];
  const float* W1  = (const float*)d_in[1];
  const float* b1  = (const float*)d_in[2];
  const float* Wmu = (const float*)d_in[3];
  const float* bmu = (const float*)d_in[4];
  const float* Wls = (const float*)d_in[5];
  const float* bls = (const float*)d_in[6];
  float* out = (float*)d_out;

  const int B = in_sizes[0] / D;  // 8192

  if (ws_size >= WS_NEED) {
    iaf_prep<<<8, 256, 0, stream>>>(W1, Wmu, Wls, (uint4*)d_ws);
    const int grid = (B + 31) / 32;  // 256
    iaf_main<<<grid, 1024, 0, stream>>>(x, b1, bmu, bls, (const uint4*)d_ws, out, B);
  } else {
    const int grid = (B + FRPB - 1) / FRPB;  // 512
    iaf_fb<<<grid, FNTHR, 0, stream>>>(x, W1, b1, Wmu, bmu, Wls, bls, out, B);
  }
}